// Round 1
// baseline (247.453 us; speedup 1.0000x reference)
//
#include <hip/hip_runtime.h>
#include <stdint.h>

// Problem constants
#define N_B   32
#define C_INN 8
#define L_IN  4096
#define C_LAT 64
#define K_EMB 512
#define E_DIM 64
#define L_OUT 2049                 // (4096 + 2*2 - 4)/2 + 1
#define M_ROWS (N_B * L_OUT)       // 65568

// d_out layout (flat float32, reference return order)
#define SZ_XREC (N_B * C_INN * L_IN)     // 1048576
#define SZ_ZE   (N_B * C_LAT * L_OUT)    // 4196352
#define OFF_XREC 0
#define OFF_ZE   (SZ_XREC)
#define OFF_ZQ   (OFF_ZE + SZ_ZE)
#define OFF_IDX  (OFF_ZQ + SZ_ZE)

// ---------------------------------------------------------------------------
// Encode: z_e[n][c][t] = conv_b[c] + sum_{ci,k} x[n][ci][2t-2+k] * conv_w[c][ci][k]
// Grid: 2048 blocks (n,c), 256 threads, 8 t per lane (t in [0,2048)), lane 255
// also does the t=2048 tail column.
// ---------------------------------------------------------------------------
__global__ __launch_bounds__(256) void encode_kernel(
    const float* __restrict__ x, const float* __restrict__ w,
    const float* __restrict__ b, float* __restrict__ z_e)
{
    const int blk  = blockIdx.x;         // 0..2047
    const int n    = blk >> 6;
    const int c    = blk & 63;
    const int lane = threadIdx.x;        // 0..255
    const int t0   = lane * 8;           // t0..t0+7

    const float* xrow = x + (size_t)n * (C_INN * L_IN);
    const float  bias = b[c];

    float acc[8];
#pragma unroll
    for (int j = 0; j < 8; ++j) acc[j] = bias;

    // interior iff x indices [2t0-4, 2t0+15] all within [0,4095]
    const bool interior = (t0 >= 2);     // t0 <= 2040 always holds
    if (interior) {
#pragma unroll
        for (int ci = 0; ci < C_INN; ++ci) {
            const float* xp = xrow + ci * L_IN + (2 * t0 - 4);  // 16B aligned
            float4 v0 = *(const float4*)(xp + 0);
            float4 v1 = *(const float4*)(xp + 4);
            float4 v2 = *(const float4*)(xp + 8);
            float4 v3 = *(const float4*)(xp + 12);
            float4 v4 = *(const float4*)(xp + 16);
            float xv[20] = {v0.x, v0.y, v0.z, v0.w, v1.x, v1.y, v1.z, v1.w,
                            v2.x, v2.y, v2.z, v2.w, v3.x, v3.y, v3.z, v3.w,
                            v4.x, v4.y, v4.z, v4.w};
            const float* wp = w + (c * C_INN + ci) * 4;  // wave-uniform -> SGPR
            const float w0 = wp[0], w1 = wp[1], w2 = wp[2], w3 = wp[3];
#pragma unroll
            for (int j = 0; j < 8; ++j) {
                // x idx = 2(t0+j)-2+k ; offset rel to (2t0-4) = 2j+2+k
                acc[j] += xv[2 * j + 2] * w0 + xv[2 * j + 3] * w1 +
                          xv[2 * j + 4] * w2 + xv[2 * j + 5] * w3;
            }
        }
    } else {
        // only lane 0 (t0 == 0): clamp + zero-select
#pragma unroll
        for (int ci = 0; ci < C_INN; ++ci) {
            const float* xp = xrow + ci * L_IN;
            const float* wp = w + (c * C_INN + ci) * 4;
#pragma unroll
            for (int j = 0; j < 8; ++j) {
#pragma unroll
                for (int k = 0; k < 4; ++k) {
                    int xi = 2 * (t0 + j) - 2 + k;
                    int xc = min(max(xi, 0), L_IN - 1);
                    float xv = xp[xc];
                    xv = (xi >= 0 && xi < L_IN) ? xv : 0.0f;
                    acc[j] += xv * wp[k];
                }
            }
        }
    }

    float* zrow = z_e + ((size_t)(n * C_LAT + c)) * L_OUT;
#pragma unroll
    for (int j = 0; j < 8; ++j) zrow[t0 + j] = acc[j];

    if (lane == 255) {
        // t = 2048: x idx 4094+k, only k=0,1 in-bounds
        float a = bias;
#pragma unroll
        for (int ci = 0; ci < C_INN; ++ci) {
            const float* xp = xrow + ci * L_IN;
            const float* wp = w + (c * C_INN + ci) * 4;
            a += xp[4094] * wp[0] + xp[4095] * wp[1];
        }
        zrow[2048] = a;
    }
}

// ---------------------------------------------------------------------------
// Quantize: per row r=(n,t), argmin_k( 0.5*||cb_k||^2 - z_r . cb_k ).
// Block = 256 thr = 4 waves; block owns 64 rows (lane = row), wave = code
// chunk of 128. Codebook reads are wave-uniform -> scalar loads. Cross-wave
// combine via packed u64 min in LDS. Then all 4 waves write z_q (16 chans
// each) and wave 0 writes indices (as float).
// ---------------------------------------------------------------------------
__global__ __launch_bounds__(256) void quantize_kernel(
    const float* __restrict__ z_e, const float* __restrict__ cb,
    float* __restrict__ z_q, float* __restrict__ idx_out)
{
    __shared__ float s_cbh[K_EMB];                       // 0.5*||cb_k||^2
    __shared__ unsigned long long s_best[4][64];

    const int tid  = threadIdx.x;
    const int wave = tid >> 6;
    const int lane = tid & 63;
    const int wq   = __builtin_amdgcn_readfirstlane(wave);  // wave-uniform

    // 0.5*||cb||^2 into LDS (each thread: 2 codes)
    for (int k = tid; k < K_EMB; k += 256) {
        const float4* cp = (const float4*)(cb + (size_t)k * E_DIM);
        float s = 0.0f;
#pragma unroll
        for (int d = 0; d < E_DIM / 4; ++d) {
            float4 v = cp[d];
            s += v.x * v.x + v.y * v.y + v.z * v.z + v.w * v.w;
        }
        s_cbh[k] = 0.5f * s;
    }
    __syncthreads();

    const int  r      = blockIdx.x * 64 + lane;
    const bool active = (r < M_ROWS);
    const unsigned rr = active ? (unsigned)r : 0u;
    const unsigned n  = rr / 2049u;
    const unsigned t  = rr - n * 2049u;

    // load this row's 64 latent channels into VGPRs (coalesced across lanes)
    const float* zp = z_e + (size_t)n * (C_LAT * L_OUT) + t;
    float z[E_DIM];
#pragma unroll
    for (int d = 0; d < E_DIM; ++d) z[d] = zp[(size_t)d * L_OUT];

    const int    k0  = wq * 128;
    const float* cbw = cb + (size_t)k0 * E_DIM;
    float best_m = INFINITY;
    int   best_k = 0;

    for (int k = 0; k < 128; k += 2) {
        const float* c0 = cbw + (size_t)k * E_DIM;   // wave-uniform -> s_load
        const float* c1 = c0 + E_DIM;
        float d0 = 0.0f, d1 = 0.0f;
#pragma unroll
        for (int d = 0; d < E_DIM; ++d) {
            d0 += z[d] * c0[d];
            d1 += z[d] * c1[d];
        }
        const float m0 = s_cbh[k0 + k] - d0;
        const float m1 = s_cbh[k0 + k + 1] - d1;
        if (m0 < best_m) { best_m = m0; best_k = k0 + k; }
        if (m1 < best_m) { best_m = m1; best_k = k0 + k + 1; }
    }

    // pack: order-preserving float bits in high 32, k in low 32 (ties -> min k
    // == first occurrence, matching jnp.argmin)
    unsigned um = __float_as_uint(best_m);
    um = (um & 0x80000000u) ? ~um : (um | 0x80000000u);
    unsigned long long packed =
        ((unsigned long long)um << 32) | (unsigned)best_k;
    if (!active) packed = ~0ULL;
    s_best[wave][lane] = packed;
    __syncthreads();

    unsigned long long p = s_best[0][lane];
    p = min(p, s_best[1][lane]);
    p = min(p, s_best[2][lane]);
    p = min(p, s_best[3][lane]);
    const int fk = (int)(unsigned)p;

    if (active) {
        const float* csel = cb + (size_t)fk * E_DIM;
        float* zq = z_q + ((size_t)(n * C_LAT + wave * 16)) * L_OUT + t;
#pragma unroll
        for (int j = 0; j < 16; ++j)
            zq[(size_t)j * L_OUT] = csel[wave * 16 + j];
        if (wave == 0) idx_out[r] = (float)fk;
    }
}

// ---------------------------------------------------------------------------
// Decode (ConvTranspose1d): x_rec[n][co][t] = tconv_b[co]
//   + sum_{ci,s,k: t = 2s-2+k, 0<=k<4} z_q[n][ci][s] * tconv_w[ci][co][k]
// Every tap is in-bounds (s in [0,2048]). Grid: 256 blocks (n,co), 256 thr;
// each lane owns s-base sp0=8*tid -> outputs t in [2*sp0, 2*sp0+16).
// ---------------------------------------------------------------------------
__global__ __launch_bounds__(256) void decode_kernel(
    const float* __restrict__ zq, const float* __restrict__ w,
    const float* __restrict__ b, float* __restrict__ xr)
{
    const int blk = blockIdx.x;      // 0..255
    const int n   = blk >> 3;
    const int co  = blk & 7;
    const int tid = threadIdx.x;
    const int sp0 = tid * 8;         // s in [sp0, sp0+8]

    const float* zn   = zq + (size_t)n * (C_LAT * L_OUT);
    const float  bias = b[co];

    float accE[8], accO[8];
#pragma unroll
    for (int j = 0; j < 8; ++j) { accE[j] = bias; accO[j] = bias; }

    for (int ci = 0; ci < C_LAT; ++ci) {
        const float* zp = zn + (size_t)ci * L_OUT + sp0;  // 4B aligned
        float4 a0 = *(const float4*)(zp);      // HW: dwordx4 needs only 4B align
        float4 a1 = *(const float4*)(zp + 4);
        float  z8 = zp[8];
        float zv[9] = {a0.x, a0.y, a0.z, a0.w, a1.x, a1.y, a1.z, a1.w, z8};
        const float* wp = w + (ci * C_INN + co) * 4;      // wave-uniform
        const float w0 = wp[0], w1 = wp[1], w2 = wp[2], w3 = wp[3];
#pragma unroll
        for (int j = 0; j < 8; ++j) {
            // t=2(sp0+j):   s=sp0+j (k=2), s=sp0+j+1 (k=0)
            // t=2(sp0+j)+1: s=sp0+j (k=3), s=sp0+j+1 (k=1)
            accE[j] += zv[j] * w2 + zv[j + 1] * w0;
            accO[j] += zv[j] * w3 + zv[j + 1] * w1;
        }
    }

    float* xrow = xr + ((size_t)(n * C_INN + co)) * L_IN + 2 * sp0;  // 16B aligned
#pragma unroll
    for (int j = 0; j < 4; ++j) {
        float4 o0 = make_float4(accE[2 * j], accO[2 * j],
                                accE[2 * j + 1], accO[2 * j + 1]);
        *(float4*)(xrow + 4 * j) = o0;
    }
}

// ---------------------------------------------------------------------------
extern "C" void kernel_launch(void* const* d_in, const int* in_sizes, int n_in,
                              void* d_out, int out_size, void* d_ws, size_t ws_size,
                              hipStream_t stream) {
    const float* x        = (const float*)d_in[0];
    const float* conv_w   = (const float*)d_in[1];
    const float* conv_b   = (const float*)d_in[2];
    const float* codebook = (const float*)d_in[3];
    const float* tconv_w  = (const float*)d_in[4];
    const float* tconv_b  = (const float*)d_in[5];

    float* out   = (float*)d_out;
    float* x_rec = out + OFF_XREC;
    float* z_e   = out + OFF_ZE;
    float* z_q   = out + OFF_ZQ;
    float* idxs  = out + OFF_IDX;

    encode_kernel<<<N_B * C_LAT, 256, 0, stream>>>(x, conv_w, conv_b, z_e);
    quantize_kernel<<<(M_ROWS + 63) / 64, 256, 0, stream>>>(z_e, codebook, z_q, idxs);
    decode_kernel<<<N_B * C_INN, 256, 0, stream>>>(z_q, tconv_w, tconv_b, x_rec);
}

// Round 2
// 233.833 us; speedup vs baseline: 1.0582x; 1.0582x over previous
//
#include <hip/hip_runtime.h>
#include <stdint.h>

// Problem constants
#define N_B   32
#define C_INN 8
#define L_IN  4096
#define C_LAT 64
#define K_EMB 512
#define E_DIM 64
#define L_OUT 2049                 // (4096 + 2*2 - 4)/2 + 1
#define M_ROWS (N_B * L_OUT)       // 65568

// d_out layout (flat float32, reference return order)
#define SZ_XREC (N_B * C_INN * L_IN)     // 1048576
#define SZ_ZE   (N_B * C_LAT * L_OUT)    // 4196352
#define OFF_XREC 0
#define OFF_ZE   (SZ_XREC)
#define OFF_ZQ   (OFF_ZE + SZ_ZE)
#define OFF_IDX  (OFF_ZQ + SZ_ZE)

// ---------------------------------------------------------------------------
// Encode: z_e[n][c][t] = conv_b[c] + sum_{ci,k} x[n][ci][2t-2+k] * conv_w[c][ci][k]
// Grid: 2048 blocks (n,c), 256 threads, 8 t per lane (t in [0,2048)), lane 255
// also does the t=2048 tail column.
// ---------------------------------------------------------------------------
__global__ __launch_bounds__(256) void encode_kernel(
    const float* __restrict__ x, const float* __restrict__ w,
    const float* __restrict__ b, float* __restrict__ z_e)
{
    const int blk  = blockIdx.x;         // 0..2047
    const int n    = blk >> 6;
    const int c    = blk & 63;
    const int lane = threadIdx.x;        // 0..255
    const int t0   = lane * 8;           // t0..t0+7

    const float* xrow = x + (size_t)n * (C_INN * L_IN);
    const float  bias = b[c];

    float acc[8];
#pragma unroll
    for (int j = 0; j < 8; ++j) acc[j] = bias;

    const bool interior = (t0 >= 2);     // t0 <= 2040 always holds
    if (interior) {
#pragma unroll
        for (int ci = 0; ci < C_INN; ++ci) {
            const float* xp = xrow + ci * L_IN + (2 * t0 - 4);  // 16B aligned
            float4 v0 = *(const float4*)(xp + 0);
            float4 v1 = *(const float4*)(xp + 4);
            float4 v2 = *(const float4*)(xp + 8);
            float4 v3 = *(const float4*)(xp + 12);
            float4 v4 = *(const float4*)(xp + 16);
            float xv[20] = {v0.x, v0.y, v0.z, v0.w, v1.x, v1.y, v1.z, v1.w,
                            v2.x, v2.y, v2.z, v2.w, v3.x, v3.y, v3.z, v3.w,
                            v4.x, v4.y, v4.z, v4.w};
            const float* wp = w + (c * C_INN + ci) * 4;  // wave-uniform -> SGPR
            const float w0 = wp[0], w1 = wp[1], w2 = wp[2], w3 = wp[3];
#pragma unroll
            for (int j = 0; j < 8; ++j) {
                acc[j] += xv[2 * j + 2] * w0 + xv[2 * j + 3] * w1 +
                          xv[2 * j + 4] * w2 + xv[2 * j + 5] * w3;
            }
        }
    } else {
        // only lane 0 (t0 == 0): clamp + zero-select
#pragma unroll
        for (int ci = 0; ci < C_INN; ++ci) {
            const float* xp = xrow + ci * L_IN;
            const float* wp = w + (c * C_INN + ci) * 4;
#pragma unroll
            for (int j = 0; j < 8; ++j) {
#pragma unroll
                for (int k = 0; k < 4; ++k) {
                    int xi = 2 * (t0 + j) - 2 + k;
                    int xc = min(max(xi, 0), L_IN - 1);
                    float xv = xp[xc];
                    xv = (xi >= 0 && xi < L_IN) ? xv : 0.0f;
                    acc[j] += xv * wp[k];
                }
            }
        }
    }

    float* zrow = z_e + ((size_t)(n * C_LAT + c)) * L_OUT;
#pragma unroll
    for (int j = 0; j < 8; ++j) zrow[t0 + j] = acc[j];

    if (lane == 255) {
        // t = 2048: x idx 4094+k, only k=0,1 in-bounds
        float a = bias;
#pragma unroll
        for (int ci = 0; ci < C_INN; ++ci) {
            const float* xp = xrow + ci * L_IN;
            const float* wp = w + (c * C_INN + ci) * 4;
            a += xp[4094] * wp[0] + xp[4095] * wp[1];
        }
        zrow[2048] = a;
    }
}

// ---------------------------------------------------------------------------
// Quantize: per row r=(n,t), argmin_k( 0.5*||cb_k||^2 - z_r . cb_k ).
// Block = 256 thr = 4 waves; block owns 64 rows (lane = row), wave = code
// chunk of 128, processed 4 codes at a time (4 independent FMA chains).
// __launch_bounds__(256,4) -> up to 128 VGPRs so z[64] stays register-resident
// (round 1: default heuristic capped VGPRs at 64, z spilled, kernel became
//  L1/L2-BW bound at ~4.3 GB -> 119 us).
// Codebook reads are wave-uniform -> scalar loads. Cross-wave combine via
// packed u64 min in LDS.
// ---------------------------------------------------------------------------
__global__ __launch_bounds__(256, 4) void quantize_kernel(
    const float* __restrict__ z_e, const float* __restrict__ cb,
    float* __restrict__ z_q, float* __restrict__ idx_out)
{
    __shared__ float s_cbh[K_EMB];                       // 0.5*||cb_k||^2
    __shared__ unsigned long long s_best[4][64];

    const int tid  = threadIdx.x;
    const int wave = tid >> 6;
    const int lane = tid & 63;
    const int wq   = __builtin_amdgcn_readfirstlane(wave);  // wave-uniform

    // 0.5*||cb||^2 into LDS (each thread: 2 codes)
    for (int k = tid; k < K_EMB; k += 256) {
        const float4* cp = (const float4*)(cb + (size_t)k * E_DIM);
        float s = 0.0f;
#pragma unroll
        for (int d = 0; d < E_DIM / 4; ++d) {
            float4 v = cp[d];
            s += v.x * v.x + v.y * v.y + v.z * v.z + v.w * v.w;
        }
        s_cbh[k] = 0.5f * s;
    }
    __syncthreads();

    const int  r      = blockIdx.x * 64 + lane;
    const bool active = (r < M_ROWS);
    const unsigned rr = active ? (unsigned)r : 0u;
    const unsigned n  = rr / 2049u;
    const unsigned t  = rr - n * 2049u;

    // this row's 64 latent channels, register-resident (coalesced across lanes)
    const float* zp = z_e + (size_t)n * (C_LAT * L_OUT) + t;
    float z[E_DIM];
#pragma unroll
    for (int d = 0; d < E_DIM; ++d) z[d] = zp[(size_t)d * L_OUT];

    const int    k0  = wq * 128;
    const float* cbw = cb + (size_t)k0 * E_DIM;
    float best_m = INFINITY;
    int   best_k = 0;

    for (int k = 0; k < 128; k += 4) {
        const float* c0 = cbw + (size_t)k * E_DIM;   // wave-uniform -> s_load
        float d0 = 0.0f, d1 = 0.0f, d2 = 0.0f, d3 = 0.0f;
#pragma unroll
        for (int d = 0; d < E_DIM; ++d) {
            const float zd = z[d];
            d0 += zd * c0[d];
            d1 += zd * c0[d + E_DIM];
            d2 += zd * c0[d + 2 * E_DIM];
            d3 += zd * c0[d + 3 * E_DIM];
        }
        const float m0 = s_cbh[k0 + k + 0] - d0;
        const float m1 = s_cbh[k0 + k + 1] - d1;
        const float m2 = s_cbh[k0 + k + 2] - d2;
        const float m3 = s_cbh[k0 + k + 3] - d3;
        // sequential compare preserves first-occurrence tie-break (jnp.argmin)
        if (m0 < best_m) { best_m = m0; best_k = k0 + k + 0; }
        if (m1 < best_m) { best_m = m1; best_k = k0 + k + 1; }
        if (m2 < best_m) { best_m = m2; best_k = k0 + k + 2; }
        if (m3 < best_m) { best_m = m3; best_k = k0 + k + 3; }
    }

    // pack: order-preserving float bits in high 32, k in low 32
    unsigned um = __float_as_uint(best_m);
    um = (um & 0x80000000u) ? ~um : (um | 0x80000000u);
    unsigned long long packed =
        ((unsigned long long)um << 32) | (unsigned)best_k;
    if (!active) packed = ~0ULL;
    s_best[wave][lane] = packed;
    __syncthreads();

    unsigned long long p = s_best[0][lane];
    unsigned long long q1 = s_best[1][lane];
    unsigned long long q2 = s_best[2][lane];
    unsigned long long q3 = s_best[3][lane];
    p = (q1 < p) ? q1 : p;
    p = (q2 < p) ? q2 : p;
    p = (q3 < p) ? q3 : p;
    const int fk = (int)(unsigned)p;

    if (active) {
        const float* csel = cb + (size_t)fk * E_DIM;
        float* zq = z_q + ((size_t)(n * C_LAT + wave * 16)) * L_OUT + t;
#pragma unroll
        for (int j = 0; j < 16; ++j)
            zq[(size_t)j * L_OUT] = csel[wave * 16 + j];
        if (wave == 0) idx_out[r] = (float)fk;
    }
}

// ---------------------------------------------------------------------------
// Decode (ConvTranspose1d): x_rec[n][co][t] = tconv_b[co]
//   + sum_{ci,s,k: t = 2s-2+k} z_q[n][ci][s] * tconv_w[ci][co][k]
// Re-gridded round 2: 2048 blocks (n x co x 8 s-chunks), one s per lane ->
// 8 blocks/CU (round 1: 256 blocks = 1 block/CU = latency-bound).
// Lane s writes t=2s (z[s]*w2 + z[s+1]*w0) and t=2s+1 (z[s]*w3 + z[s+1]*w1);
// s in [0,2047], s+1 <= 2048 always valid, t covers [0,4095].
// ---------------------------------------------------------------------------
__global__ __launch_bounds__(256) void decode_kernel(
    const float* __restrict__ zq, const float* __restrict__ w,
    const float* __restrict__ b, float* __restrict__ xr)
{
    const int blk   = blockIdx.x;           // 0..2047
    const int chunk = blk & 7;
    const int co    = (blk >> 3) & 7;
    const int n     = blk >> 6;
    const int s     = chunk * 256 + threadIdx.x;   // 0..2047

    const float* zn = zq + (size_t)n * (C_LAT * L_OUT) + s;
    float accE = b[co];
    float accO = accE;

#pragma unroll 4
    for (int ci = 0; ci < C_LAT; ++ci) {
        const float z0 = zn[(size_t)ci * L_OUT];
        const float z1 = zn[(size_t)ci * L_OUT + 1];
        const float* wp = w + (ci * C_INN + co) * 4;   // wave-uniform -> SGPR
        accE += z0 * wp[2] + z1 * wp[0];
        accO += z0 * wp[3] + z1 * wp[1];
    }

    float* xrow = xr + ((size_t)(n * C_INN + co)) * L_IN;
    *(float2*)(xrow + 2 * s) = make_float2(accE, accO);   // 8B aligned
}

// ---------------------------------------------------------------------------
extern "C" void kernel_launch(void* const* d_in, const int* in_sizes, int n_in,
                              void* d_out, int out_size, void* d_ws, size_t ws_size,
                              hipStream_t stream) {
    const float* x        = (const float*)d_in[0];
    const float* conv_w   = (const float*)d_in[1];
    const float* conv_b   = (const float*)d_in[2];
    const float* codebook = (const float*)d_in[3];
    const float* tconv_w  = (const float*)d_in[4];
    const float* tconv_b  = (const float*)d_in[5];

    float* out   = (float*)d_out;
    float* x_rec = out + OFF_XREC;
    float* z_e   = out + OFF_ZE;
    float* z_q   = out + OFF_ZQ;
    float* idxs  = out + OFF_IDX;

    encode_kernel<<<N_B * C_LAT, 256, 0, stream>>>(x, conv_w, conv_b, z_e);
    quantize_kernel<<<(M_ROWS + 63) / 64, 256, 0, stream>>>(z_e, codebook, z_q, idxs);
    decode_kernel<<<N_B * C_INN * 8, 256, 0, stream>>>(z_q, tconv_w, tconv_b, x_rec);
}

// Round 3
// 225.545 us; speedup vs baseline: 1.0971x; 1.0367x over previous
//
#include <hip/hip_runtime.h>
#include <stdint.h>

// Problem constants
#define N_B   32
#define C_INN 8
#define L_IN  4096
#define C_LAT 64
#define K_EMB 512
#define E_DIM 64
#define L_OUT 2049                 // (4096 + 2*2 - 4)/2 + 1
#define M_ROWS (N_B * L_OUT)       // 65568

// d_out layout (flat float32, reference return order)
#define SZ_XREC (N_B * C_INN * L_IN)     // 1048576
#define SZ_ZE   (N_B * C_LAT * L_OUT)    // 4196352
#define OFF_XREC 0
#define OFF_ZE   (SZ_XREC)
#define OFF_ZQ   (OFF_ZE + SZ_ZE)
#define OFF_IDX  (OFF_ZQ + SZ_ZE)

// ---------------------------------------------------------------------------
// Encode: z_e[n][c][t] = conv_b[c] + sum_{ci,k} x[n][ci][2t-2+k] * conv_w[c][ci][k]
// Round 3 rewrite: lane <-> one t (t = slice*256 + tid, contiguous across
// lanes -> coalesced float4 x loads, 8B lane stride = 2 lines/instr instead of
// round 1-2's 32 lines/instr). Each lane holds its 32 x taps (8 ci x 4)
// register-resident (asm-pinned against rematerialization) and loops over all
// 64 output channels with wave-uniform weights (s_load -> v_fma v,s,v).
// Grid: 32 n x 9 slices of 256 t (slice 8 covers only t=2048).
// ---------------------------------------------------------------------------
__global__ __launch_bounds__(256, 4) void encode_kernel(
    const float* __restrict__ x, const float* __restrict__ w,
    const float* __restrict__ b, float* __restrict__ z_e)
{
    const int blk   = blockIdx.x;        // 0..287
    const int n     = blk / 9;
    const int slice = blk - n * 9;
    const int t     = slice * 256 + threadIdx.x;   // 0..2303
    const bool valid = (t < L_OUT);

    const float* xrow = x + (size_t)n * (C_INN * L_IN);

    // x taps: xi = 2t-2 .. 2t+1 per ci
    float xv[C_INN][4];
    const bool fast = (t >= 1 && t <= 2047);  // 2t-2 >= 0 and 2t+1 <= 4095
    if (fast) {
#pragma unroll
        for (int ci = 0; ci < C_INN; ++ci) {
            float4 v = *(const float4*)(xrow + ci * L_IN + (2 * t - 2));
            xv[ci][0] = v.x; xv[ci][1] = v.y; xv[ci][2] = v.z; xv[ci][3] = v.w;
        }
    } else {
#pragma unroll
        for (int ci = 0; ci < C_INN; ++ci) {
#pragma unroll
            for (int k = 0; k < 4; ++k) {
                int xi = 2 * t - 2 + k;
                int xc = min(max(xi, 0), L_IN - 1);
                float v = valid ? xrow[ci * L_IN + xc] : 0.0f;
                xv[ci][k] = (xi >= 0 && xi < L_IN) ? v : 0.0f;
            }
        }
    }
    // Pin taps in VGPRs: opaque def prevents the allocator from sinking the
    // loads into the c-loop (the round-1/2 quantize failure mode).
#pragma unroll
    for (int ci = 0; ci < C_INN; ++ci)
#pragma unroll
        for (int k = 0; k < 4; ++k)
            asm volatile("" : "+v"(xv[ci][k]));

    float* zcol = z_e + (size_t)n * (C_LAT * L_OUT) + t;

    for (int c4 = 0; c4 < C_LAT; c4 += 4) {
        float a0 = b[c4 + 0], a1 = b[c4 + 1], a2 = b[c4 + 2], a3 = b[c4 + 3];
#pragma unroll
        for (int ci = 0; ci < C_INN; ++ci) {
            const float* w0 = w + ((c4 + 0) * C_INN + ci) * 4;  // uniform
            const float* w1 = w + ((c4 + 1) * C_INN + ci) * 4;
            const float* w2 = w + ((c4 + 2) * C_INN + ci) * 4;
            const float* w3 = w + ((c4 + 3) * C_INN + ci) * 4;
#pragma unroll
            for (int k = 0; k < 4; ++k) {
                const float xk = xv[ci][k];
                a0 += xk * w0[k];
                a1 += xk * w1[k];
                a2 += xk * w2[k];
                a3 += xk * w3[k];
            }
        }
        if (valid) {
            zcol[(size_t)(c4 + 0) * L_OUT] = a0;
            zcol[(size_t)(c4 + 1) * L_OUT] = a1;
            zcol[(size_t)(c4 + 2) * L_OUT] = a2;
            zcol[(size_t)(c4 + 3) * L_OUT] = a3;
        }
    }
}

// ---------------------------------------------------------------------------
// Quantize: per row r=(n,t), argmin_k( 0.5*||cb_k||^2 - z_r . cb_k ).
// Block = 256 thr = 4 waves; block owns 64 rows (lane = row), wave = code
// chunk of 128, processed 4 codes at a time (4 independent FMA chains).
// Round 3: z[64] is asm-pinned into VGPRs. Round 1/2 evidence: VGPR_Count
// 64/60 despite z[64] -> the compiler rematerialized the z loads inside the
// k-loop, making the kernel L1-bound (113 us vs 27 us FMA floor).
// Codebook reads are wave-uniform -> scalar loads. Cross-wave combine via
// packed u64 min in LDS.
// ---------------------------------------------------------------------------
__global__ __launch_bounds__(256, 4) void quantize_kernel(
    const float* __restrict__ z_e, const float* __restrict__ cb,
    float* __restrict__ z_q, float* __restrict__ idx_out)
{
    __shared__ float s_cbh[K_EMB];                       // 0.5*||cb_k||^2
    __shared__ unsigned long long s_best[4][64];

    const int tid  = threadIdx.x;
    const int wave = tid >> 6;
    const int lane = tid & 63;
    const int wq   = __builtin_amdgcn_readfirstlane(wave);  // wave-uniform

    // 0.5*||cb||^2 into LDS (each thread: 2 codes)
    for (int k = tid; k < K_EMB; k += 256) {
        const float4* cp = (const float4*)(cb + (size_t)k * E_DIM);
        float s = 0.0f;
#pragma unroll
        for (int d = 0; d < E_DIM / 4; ++d) {
            float4 v = cp[d];
            s += v.x * v.x + v.y * v.y + v.z * v.z + v.w * v.w;
        }
        s_cbh[k] = 0.5f * s;
    }
    __syncthreads();

    const int  r      = blockIdx.x * 64 + lane;
    const bool active = (r < M_ROWS);
    const unsigned rr = active ? (unsigned)r : 0u;
    const unsigned n  = rr / 2049u;
    const unsigned t  = rr - n * 2049u;

    // this row's 64 latent channels, register-resident (coalesced across lanes)
    const float* zp = z_e + (size_t)n * (C_LAT * L_OUT) + t;
    float z[E_DIM];
#pragma unroll
    for (int d = 0; d < E_DIM; ++d) z[d] = zp[(size_t)d * L_OUT];
    // Opaque def: forbid rematerialization/sinking of the z loads.
#pragma unroll
    for (int d = 0; d < E_DIM; ++d) asm volatile("" : "+v"(z[d]));

    const int    k0  = wq * 128;
    const float* cbw = cb + (size_t)k0 * E_DIM;
    float best_m = INFINITY;
    int   best_k = 0;

    for (int k = 0; k < 128; k += 4) {
        const float* c0 = cbw + (size_t)k * E_DIM;   // wave-uniform -> s_load
        float d0 = 0.0f, d1 = 0.0f, d2 = 0.0f, d3 = 0.0f;
#pragma unroll
        for (int d = 0; d < E_DIM; ++d) {
            const float zd = z[d];
            d0 += zd * c0[d];
            d1 += zd * c0[d + E_DIM];
            d2 += zd * c0[d + 2 * E_DIM];
            d3 += zd * c0[d + 3 * E_DIM];
        }
        const float m0 = s_cbh[k0 + k + 0] - d0;
        const float m1 = s_cbh[k0 + k + 1] - d1;
        const float m2 = s_cbh[k0 + k + 2] - d2;
        const float m3 = s_cbh[k0 + k + 3] - d3;
        // sequential compare preserves first-occurrence tie-break (jnp.argmin)
        if (m0 < best_m) { best_m = m0; best_k = k0 + k + 0; }
        if (m1 < best_m) { best_m = m1; best_k = k0 + k + 1; }
        if (m2 < best_m) { best_m = m2; best_k = k0 + k + 2; }
        if (m3 < best_m) { best_m = m3; best_k = k0 + k + 3; }
    }

    // pack: order-preserving float bits in high 32, k in low 32
    unsigned um = __float_as_uint(best_m);
    um = (um & 0x80000000u) ? ~um : (um | 0x80000000u);
    unsigned long long packed =
        ((unsigned long long)um << 32) | (unsigned)best_k;
    if (!active) packed = ~0ULL;
    s_best[wave][lane] = packed;
    __syncthreads();

    unsigned long long p = s_best[0][lane];
    unsigned long long q1 = s_best[1][lane];
    unsigned long long q2 = s_best[2][lane];
    unsigned long long q3 = s_best[3][lane];
    p = (q1 < p) ? q1 : p;
    p = (q2 < p) ? q2 : p;
    p = (q3 < p) ? q3 : p;
    const int fk = (int)(unsigned)p;

    if (active) {
        const float* csel = cb + (size_t)fk * E_DIM;
        float* zq = z_q + ((size_t)(n * C_LAT + wave * 16)) * L_OUT + t;
#pragma unroll
        for (int j = 0; j < 16; ++j)
            zq[(size_t)j * L_OUT] = csel[wave * 16 + j];
        if (wave == 0) idx_out[r] = (float)fk;
    }
}

// ---------------------------------------------------------------------------
// Decode (ConvTranspose1d): x_rec[n][co][t] = tconv_b[co]
//   + sum_{ci,s,k: t = 2s-2+k} z_q[n][ci][s] * tconv_w[ci][co][k]
// 2048 blocks (n x co x 8 s-chunks), one s per lane -> 8 blocks/CU.
// Lane s writes t=2s (z[s]*w2 + z[s+1]*w0) and t=2s+1 (z[s]*w3 + z[s+1]*w1).
// ---------------------------------------------------------------------------
__global__ __launch_bounds__(256) void decode_kernel(
    const float* __restrict__ zq, const float* __restrict__ w,
    const float* __restrict__ b, float* __restrict__ xr)
{
    const int blk   = blockIdx.x;           // 0..2047
    const int chunk = blk & 7;
    const int co    = (blk >> 3) & 7;
    const int n     = blk >> 6;
    const int s     = chunk * 256 + threadIdx.x;   // 0..2047

    const float* zn = zq + (size_t)n * (C_LAT * L_OUT) + s;
    float accE = b[co];
    float accO = accE;

#pragma unroll 4
    for (int ci = 0; ci < C_LAT; ++ci) {
        const float z0 = zn[(size_t)ci * L_OUT];
        const float z1 = zn[(size_t)ci * L_OUT + 1];
        const float* wp = w + (ci * C_INN + co) * 4;   // wave-uniform -> SGPR
        accE += z0 * wp[2] + z1 * wp[0];
        accO += z0 * wp[3] + z1 * wp[1];
    }

    float* xrow = xr + ((size_t)(n * C_INN + co)) * L_IN;
    *(float2*)(xrow + 2 * s) = make_float2(accE, accO);   // 8B aligned
}

// ---------------------------------------------------------------------------
extern "C" void kernel_launch(void* const* d_in, const int* in_sizes, int n_in,
                              void* d_out, int out_size, void* d_ws, size_t ws_size,
                              hipStream_t stream) {
    const float* x        = (const float*)d_in[0];
    const float* conv_w   = (const float*)d_in[1];
    const float* conv_b   = (const float*)d_in[2];
    const float* codebook = (const float*)d_in[3];
    const float* tconv_w  = (const float*)d_in[4];
    const float* tconv_b  = (const float*)d_in[5];

    float* out   = (float*)d_out;
    float* x_rec = out + OFF_XREC;
    float* z_e   = out + OFF_ZE;
    float* z_q   = out + OFF_ZQ;
    float* idxs  = out + OFF_IDX;

    encode_kernel<<<N_B * 9, 256, 0, stream>>>(x, conv_w, conv_b, z_e);
    quantize_kernel<<<(M_ROWS + 63) / 64, 256, 0, stream>>>(z_e, codebook, z_q, idxs);
    decode_kernel<<<N_B * C_INN * 8, 256, 0, stream>>>(z_q, tconv_w, tconv_b, x_rec);
}